// Round 2
// baseline (1178.161 us; speedup 1.0000x reference)
//
#include <hip/hip_runtime.h>
#include <math.h>

#define BATCH 8192
#define M 200
#define E 64
#define H1 96    // ADIM/2
#define F1 128   // FEA/2
#define F2 85    // FEA/3
#define F3 64    // FEA/4
#define SH 72    // WbT row stride in halfs
#define MT 13    // ceil(200/16) m-tiles

typedef _Float16 half8_t __attribute__((ext_vector_type(8)));
typedef float floatx4 __attribute__((ext_vector_type(4)));

// One block per batch row b.
//  A) fold WbT = (aW1a + diag(tgt)aW1b)^T (fp16), be = ab1 + tgt@aW1c
//  B) per wave: tiles processed in PAIRS (wv,wv+4) then (wv+8,wv+12):
//     both tiles' hist rows loaded together (8 dwordx4 in flight), next
//     pair prefetched during compute, first pair issued at kernel entry.
//     B-fragments are read from LDS per-nt (keeps VGPR pressure low
//     enough that the prefetch actually lives in registers — R1 showed
//     the 64-VGPR budget spilled it to scratch).
//     amdgpu_waves_per_eu(4,4) pins the allocator at a 128-VGPR budget.
//  C) in-quad butterfly of tk, per-wave partials to LDS scratch, reduce
//  D) fused MLP head 256->128->85->64->sigmoid
__global__ __launch_bounds__(256)
__attribute__((amdgpu_waves_per_eu(4, 4)))
void din_kernel(
    const float* __restrict__ hist, const float* __restrict__ target,
    const float* __restrict__ other,
    const float* __restrict__ aW1, const float* __restrict__ ab1,
    const float* __restrict__ aW2, const float* __restrict__ ab2,
    const float* __restrict__ oW1, const float* __restrict__ ob1,
    const float* __restrict__ oW2, const float* __restrict__ ob2,
    const float* __restrict__ oW3, const float* __restrict__ ob3,
    const float* __restrict__ fW,  const float* __restrict__ fb,
    float* __restrict__ out)
{
    __shared__ _Float16 WbT[H1 * SH];      // 13824 B
    __shared__ float tgtS[E];
    __shared__ float beS[H1];
    __shared__ float aW2S[H1];
    __shared__ float xS[256];
    __shared__ float scr[512];
    __shared__ float h1S[F1];
    __shared__ float h2S[F2];
    __shared__ float ab2S;

    const int t = threadIdx.x;
    const int b = blockIdx.x;
    const int lane = t & 63;
    const int wv   = t >> 6;
    const int quad = lane >> 4;
    const int lm   = lane & 15;

    // ---- entry prefetch: first tile pair + other row ------------------
    const float* histB = hist + (size_t)b * M * E + quad * 8;
    int rowA = wv * 16 + lm;
    int rowB = rowA + 64;
    const float4* pA = (const float4*)(histB + (size_t)(rowA < M ? rowA : M - 1) * E);
    const float4* pB = (const float4*)(histB + (size_t)(rowB < M ? rowB : M - 1) * E);
    float4 fA0 = pA[0], gA0 = pA[1], fA1 = pA[8], gA1 = pA[9];
    float4 fB0 = pB[0], gB0 = pB[1], fB1 = pB[8], gB1 = pB[9];
    float oth = 0.f;
    if (t >= 128) oth = other[(size_t)b * 128 + (t - 128)];

    if (t < E) tgtS[t] = target[(size_t)b * E + t];
    if (t == 0) ab2S = ab2[0];
    __syncthreads();

    // ---- Phase A: weight folds ----------------------------------------
    for (int idx = t; idx < E * H1; idx += 256) {
        int k = idx / H1, j = idx - k * H1;
        float w = aW1[idx] + tgtS[k] * aW1[E * H1 + idx];
        WbT[j * SH + k] = (_Float16)w;
    }
    if (t < H1) {
        float s0 = ab1[t], s1 = 0.f, s2 = 0.f, s3 = 0.f;
        const float* wp = aW1 + (size_t)(2 * E) * H1 + t;
        #pragma unroll 4
        for (int k = 0; k < E; k += 4) {
            s0 += tgtS[k]     * wp[(size_t)k * H1];
            s1 += tgtS[k + 1] * wp[(size_t)(k + 1) * H1];
            s2 += tgtS[k + 2] * wp[(size_t)(k + 2) * H1];
            s3 += tgtS[k + 3] * wp[(size_t)(k + 3) * H1];
        }
        beS[t] = (s0 + s1) + (s2 + s3);
        aW2S[t] = aW2[t];
    }
    __syncthreads();

    // ---- Phase B ------------------------------------------------------
    const _Float16* bfB = &WbT[lm * SH + quad * 8];  // + nt*16*SH (+32 for kk=1)
    const int qs16 = (lm >> 2) << 4;
    const int rsel = lm & 3;

    float tk0[8], tk1[8];
    #pragma unroll
    for (int j = 0; j < 8; ++j) { tk0[j] = 0.f; tk1[j] = 0.f; }

    // per-tile: MFMA over 6 nt, fused relu+aW2, butterfly-reduce, aij
    auto tile_aij = [&](const float4& f0, const float4& g0,
                        const float4& f1, const float4& g1, int row) -> float {
        half8_t a0 = { (_Float16)f0.x, (_Float16)f0.y, (_Float16)f0.z, (_Float16)f0.w,
                       (_Float16)g0.x, (_Float16)g0.y, (_Float16)g0.z, (_Float16)g0.w };
        half8_t a1 = { (_Float16)f1.x, (_Float16)f1.y, (_Float16)f1.z, (_Float16)f1.w,
                       (_Float16)g1.x, (_Float16)g1.y, (_Float16)g1.z, (_Float16)g1.w };
        float s0 = 0.f, s1 = 0.f, s2 = 0.f, s3 = 0.f;
        #pragma unroll
        for (int nt = 0; nt < 6; ++nt) {
            half8_t b0 = *(const half8_t*)(bfB + nt * (16 * SH));
            half8_t b1 = *(const half8_t*)(bfB + nt * (16 * SH) + 32);
            floatx4 acc = {0.f, 0.f, 0.f, 0.f};
            acc = __builtin_amdgcn_mfma_f32_16x16x32_f16(a0, b0, acc, 0, 0, 0);
            acc = __builtin_amdgcn_mfma_f32_16x16x32_f16(a1, b1, acc, 0, 0, 0);
            float be_n = beS[nt * 16 + lm];
            float w2   = aW2S[nt * 16 + lm];
            s0 += fmaxf(acc[0] + be_n, 0.f) * w2;
            s1 += fmaxf(acc[1] + be_n, 0.f) * w2;
            s2 += fmaxf(acc[2] + be_n, 0.f) * w2;
            s3 += fmaxf(acc[3] + be_n, 0.f) * w2;
        }
        #pragma unroll
        for (int off = 1; off < 16; off <<= 1) {
            s0 += __shfl_xor(s0, off);
            s1 += __shfl_xor(s1, off);
            s2 += __shfl_xor(s2, off);
            s3 += __shfl_xor(s3, off);
        }
        float v0 = __shfl(s0, qs16), v1 = __shfl(s1, qs16);
        float v2 = __shfl(s2, qs16), v3 = __shfl(s3, qs16);
        float aij = (rsel == 0) ? v0 : (rsel == 1) ? v1 : (rsel == 2) ? v2 : v3;
        aij += ab2S;
        return (row < M) ? aij : 0.f;
    };

    for (int mt = wv; mt < MT; mt += 8) {
        // prefetch next pair (tiles mt+8, mt+12) while computing this one
        const int nmt = mt + 8;
        float4 nfA0 = fA0, ngA0 = gA0, nfA1 = fA1, ngA1 = gA1;
        float4 nfB0 = fB0, ngB0 = gB0, nfB1 = fB1, ngB1 = gB1;
        if (nmt < MT) {
            int nrA = nmt * 16 + lm;
            int nrB = nrA + 64;
            const float4* npA = (const float4*)(histB + (size_t)(nrA < M ? nrA : M - 1) * E);
            const float4* npB = (const float4*)(histB + (size_t)(nrB < M ? nrB : M - 1) * E);
            nfA0 = npA[0]; ngA0 = npA[1]; nfA1 = npA[8]; ngA1 = npA[9];
            nfB0 = npB[0]; ngB0 = npB[1]; nfB1 = npB[8]; ngB1 = npB[9];
        }

        const float aijA = tile_aij(fA0, gA0, fA1, gA1, rowA);
        tk0[0] += fA0.x * aijA; tk0[1] += fA0.y * aijA;
        tk0[2] += fA0.z * aijA; tk0[3] += fA0.w * aijA;
        tk0[4] += gA0.x * aijA; tk0[5] += gA0.y * aijA;
        tk0[6] += gA0.z * aijA; tk0[7] += gA0.w * aijA;
        tk1[0] += fA1.x * aijA; tk1[1] += fA1.y * aijA;
        tk1[2] += fA1.z * aijA; tk1[3] += fA1.w * aijA;
        tk1[4] += gA1.x * aijA; tk1[5] += gA1.y * aijA;
        tk1[6] += gA1.z * aijA; tk1[7] += gA1.w * aijA;

        const float aijB = tile_aij(fB0, gB0, fB1, gB1, rowB);
        tk0[0] += fB0.x * aijB; tk0[1] += fB0.y * aijB;
        tk0[2] += fB0.z * aijB; tk0[3] += fB0.w * aijB;
        tk0[4] += gB0.x * aijB; tk0[5] += gB0.y * aijB;
        tk0[6] += gB0.z * aijB; tk0[7] += gB0.w * aijB;
        tk1[0] += fB1.x * aijB; tk1[1] += fB1.y * aijB;
        tk1[2] += fB1.z * aijB; tk1[3] += fB1.w * aijB;
        tk1[4] += gB1.x * aijB; tk1[5] += gB1.y * aijB;
        tk1[6] += gB1.z * aijB; tk1[7] += gB1.w * aijB;

        fA0 = nfA0; gA0 = ngA0; fA1 = nfA1; gA1 = ngA1;
        fB0 = nfB0; gB0 = ngB0; fB1 = nfB1; gB1 = ngB1;
        rowA = nmt * 16 + lm;
        rowB = rowA + 64;
    }

    // ---- Phase C: reduce tk over quad lanes, write per-wave partials --
    #pragma unroll
    for (int j = 0; j < 8; ++j) {
        #pragma unroll
        for (int off = 1; off < 16; off <<= 1) {
            tk0[j] += __shfl_xor(tk0[j], off);
            tk1[j] += __shfl_xor(tk1[j], off);
        }
    }
    if (lm == 0) {
        #pragma unroll
        for (int j = 0; j < 8; ++j) {
            scr[wv * E + quad * 8 + j]      = tk0[j];
            scr[wv * E + 32 + quad * 8 + j] = tk1[j];
        }
    }
    __syncthreads();

    // x = [tmp | target | other]
    if (t < 64)
        xS[t] = (scr[t] + scr[64 + t]) + (scr[128 + t] + scr[192 + t]);
    else if (t < 128)
        xS[t] = tgtS[t - 64];
    else
        xS[t] = oth;
    __syncthreads();

    // ---- Phase D: MLP head --------------------------------------------
    // h1: 128 outs, 256-dot; thread (g=t&31, s=t>>5): outs 4g..4g+3,
    // c in [32s, 32s+32); float4 weight loads; lane^32 combine
    {
        const int g = t & 31, s = t >> 5;
        const float* wbase = oW1 + 4 * g;
        const int c0 = s * 32;
        float ax = 0.f, ay = 0.f, az = 0.f, aw = 0.f;
        #pragma unroll 8
        for (int i = 0; i < 32; ++i) {
            const int c = c0 + i;
            float xv = xS[c];
            float4 w4 = *(const float4*)(wbase + (size_t)c * F1);
            ax += xv * w4.x; ay += xv * w4.y;
            az += xv * w4.z; aw += xv * w4.w;
        }
        ax += __shfl_xor(ax, 32);
        ay += __shfl_xor(ay, 32);
        az += __shfl_xor(az, 32);
        aw += __shfl_xor(aw, 32);
        if (lane < 32) {
            float4 r = { ax, ay, az, aw };
            *(float4*)&scr[wv * 128 + 4 * g] = r;
        }
    }
    __syncthreads();
    if (t < F1)
        h1S[t] = fmaxf((scr[t] + scr[128 + t]) + (scr[256 + t] + scr[384 + t]) + ob1[t], 0.f);
    __syncthreads();

    // h2: 85 outs, 128-dot, split 2 ways over c
    {
        const int o = t & 127, ph = t >> 7;
        if (o < F2) {
            float sA = 0.f, sB = 0.f;
            const int c0 = ph * 64;
            #pragma unroll 8
            for (int c = 0; c < 64; c += 2) {
                sA += h1S[c0 + c]     * oW2[(size_t)(c0 + c) * F2 + o];
                sB += h1S[c0 + c + 1] * oW2[(size_t)(c0 + c + 1) * F2 + o];
            }
            scr[ph * 128 + o] = sA + sB;
        }
    }
    __syncthreads();
    if (t < F2) h2S[t] = fmaxf(scr[t] + scr[128 + t] + ob2[t], 0.f);
    __syncthreads();

    // h3: 64 outs, 85-dot, split 4 ways over c (all 256 threads)
    {
        const int o = t & 63, ph = t >> 6;
        const int c0 = (85 * ph) >> 2, c1 = (85 * (ph + 1)) >> 2;
        float s = 0.f;
        for (int c = c0; c < c1; ++c)
            s += h2S[c] * oW3[(size_t)c * F3 + o];
        scr[ph * 64 + o] = s;
    }
    __syncthreads();

    if (t < 64) {
        float v = fmaxf((scr[t] + scr[64 + t]) + (scr[128 + t] + scr[192 + t]) + ob3[t], 0.f) * fW[t];
        v += __shfl_xor(v, 1);  v += __shfl_xor(v, 2);  v += __shfl_xor(v, 4);
        v += __shfl_xor(v, 8);  v += __shfl_xor(v, 16); v += __shfl_xor(v, 32);
        if (t == 0) out[b] = 1.f / (1.f + __expf(-(v + fb[0])));
    }
}

extern "C" void kernel_launch(void* const* d_in, const int* in_sizes, int n_in,
                              void* d_out, int out_size, void* d_ws, size_t ws_size,
                              hipStream_t stream) {
    const float* hist   = (const float*)d_in[0];
    const float* target = (const float*)d_in[1];
    const float* other  = (const float*)d_in[2];
    const float* aW1    = (const float*)d_in[3];
    const float* ab1    = (const float*)d_in[4];
    const float* aW2    = (const float*)d_in[5];
    const float* ab2    = (const float*)d_in[6];
    const float* oW1    = (const float*)d_in[7];
    const float* ob1    = (const float*)d_in[8];
    const float* oW2    = (const float*)d_in[9];
    const float* ob2    = (const float*)d_in[10];
    const float* oW3    = (const float*)d_in[11];
    const float* ob3    = (const float*)d_in[12];
    const float* fW     = (const float*)d_in[13];
    const float* fb     = (const float*)d_in[14];
    float* out = (float*)d_out;

    din_kernel<<<BATCH, 256, 0, stream>>>(hist, target, other,
                                          aW1, ab1, aW2, ab2,
                                          oW1, ob1, oW2, ob2, oW3, ob3,
                                          fW, fb, out);
}

// Round 3
// 785.277 us; speedup vs baseline: 1.5003x; 1.5003x over previous
//
#include <hip/hip_runtime.h>
#include <math.h>

#define BATCH 8192
#define M 200
#define E 64
#define H1 96    // ADIM/2
#define F1 128   // FEA/2
#define F2 85    // FEA/3
#define F3 64    // FEA/4
#define MT 13    // ceil(200/16) m-tiles

typedef _Float16 half8_t __attribute__((ext_vector_type(8)));
typedef float floatx4 __attribute__((ext_vector_type(4)));

// Prep kernel (once per launch): block-invariant transposed fp16 weights.
//   waT[n][k] = fp16(aW1a[k][n]),  wbT[n][k] = fp16(aW1b[k][n]),  n<96,k<64
// This removes the per-block Phase-A fold (147 KB of L2 reads serialized
// behind the target load) from the 8192-block critical path entirely.
__global__ void din_prep(const float* __restrict__ aW1,
                         _Float16* __restrict__ waT, _Float16* __restrict__ wbT)
{
    const int n = blockIdx.x;    // 0..95
    const int k = threadIdx.x;   // 0..63
    waT[n * 64 + k] = (_Float16)aW1[(size_t)k * H1 + n];
    wbT[n * 64 + k] = (_Float16)aW1[(size_t)(E + k) * H1 + n];
}

// One block per batch row b. Design constraints learned R0-R2: the
// allocator pins this kernel at 64 VGPRs (spills anything bigger), so:
// no register prefetch, no fragment hoisting, minimal live state, and
// latency is hidden with OCCUPANCY: LDS cut to ~5 KB -> 8 blocks/CU.
//  B) per wave, per 16-row tile: hist direct from global (float4),
//     h = relu(hist@aW1a + (hist*tgt)@aW1b + be) via 4 MFMAs with
//     L2-hot global weight frags; relu(+be)@aW2 -> butterfly -> aij;
//     tmp[k] accumulated in registers from the fp32 hist values
//  C) in-quad butterfly of tk, per-wave partials to LDS, reduce
//  D) fused MLP head 256->128->85->64->sigmoid
__global__ __launch_bounds__(256) void din_kernel(
    const float* __restrict__ hist, const float* __restrict__ target,
    const float* __restrict__ other,
    const _Float16* __restrict__ waT, const _Float16* __restrict__ wbT,
    const float* __restrict__ aW1, const float* __restrict__ ab1,
    const float* __restrict__ aW2, const float* __restrict__ ab2,
    const float* __restrict__ oW1, const float* __restrict__ ob1,
    const float* __restrict__ oW2, const float* __restrict__ ob2,
    const float* __restrict__ oW3, const float* __restrict__ ob3,
    const float* __restrict__ fW,  const float* __restrict__ fb,
    float* __restrict__ out)
{
    __shared__ float tgtS[E];
    __shared__ float beS[H1];
    __shared__ float aW2S[H1];
    __shared__ float xS[256];
    __shared__ float scr[512];
    __shared__ float h1S[F1];
    __shared__ float h2S[F2];
    __shared__ float ab2S;

    const int t = threadIdx.x;
    const int b = blockIdx.x;
    const int lane = t & 63;
    const int wv   = t >> 6;
    const int quad = lane >> 4;
    const int lm   = lane & 15;

    float oth = 0.f;
    if (t >= 128) oth = other[(size_t)b * 128 + (t - 128)];
    if (t < E) tgtS[t] = target[(size_t)b * E + t];
    if (t == 0) ab2S = ab2[0];
    __syncthreads();

    // be = ab1 + tgt @ aW1c  (aW1c rows are L2-hot; coalesced across t)
    if (t < H1) {
        float s0 = ab1[t], s1 = 0.f, s2 = 0.f, s3 = 0.f;
        const float* wp = aW1 + (size_t)(2 * E) * H1 + t;
        #pragma unroll 4
        for (int k = 0; k < E; k += 4) {
            s0 += tgtS[k]     * wp[(size_t)k * H1];
            s1 += tgtS[k + 1] * wp[(size_t)(k + 1) * H1];
            s2 += tgtS[k + 2] * wp[(size_t)(k + 2) * H1];
            s3 += tgtS[k + 3] * wp[(size_t)(k + 3) * H1];
        }
        beS[t] = (s0 + s1) + (s2 + s3);
        aW2S[t] = aW2[t];
    }
    __syncthreads();

    // ---- Phase B ------------------------------------------------------
    const float* histB = hist + (size_t)b * M * E + quad * 8;
    const _Float16* waB = waT + lm * 64 + quad * 8;   // + nt*1024 (+32 kk=1)
    const _Float16* wbB = wbT + lm * 64 + quad * 8;
    const float4* tgt4 = (const float4*)tgtS;
    const int qs16 = (lm >> 2) << 4;
    const int rsel = lm & 3;

    float tk0[8], tk1[8];
    #pragma unroll
    for (int j = 0; j < 8; ++j) { tk0[j] = 0.f; tk1[j] = 0.f; }

    for (int mt = wv; mt < MT; mt += 4) {
        const int row = mt * 16 + lm;
        const float4* p = (const float4*)(histB + (size_t)(row < M ? row : M - 1) * E);
        float4 f0 = p[0], g0 = p[1], f1 = p[8], g1 = p[9];

        // tgt frags: broadcast LDS reads (same addr within a quad), per
        // tile to keep register pressure under the 64-VGPR budget
        float4 T0 = tgt4[quad * 2],     T1 = tgt4[quad * 2 + 1];
        float4 T2 = tgt4[8 + quad * 2], T3 = tgt4[9 + quad * 2];

        half8_t a0 = { (_Float16)f0.x, (_Float16)f0.y, (_Float16)f0.z, (_Float16)f0.w,
                       (_Float16)g0.x, (_Float16)g0.y, (_Float16)g0.z, (_Float16)g0.w };
        half8_t a1 = { (_Float16)f1.x, (_Float16)f1.y, (_Float16)f1.z, (_Float16)f1.w,
                       (_Float16)g1.x, (_Float16)g1.y, (_Float16)g1.z, (_Float16)g1.w };
        // hist*tgt in fp32 then one fp16 rounding (same error profile as
        // the old fp32 fold -> fp16 cvt)
        half8_t a0t = { (_Float16)(f0.x * T0.x), (_Float16)(f0.y * T0.y),
                        (_Float16)(f0.z * T0.z), (_Float16)(f0.w * T0.w),
                        (_Float16)(g0.x * T1.x), (_Float16)(g0.y * T1.y),
                        (_Float16)(g0.z * T1.z), (_Float16)(g0.w * T1.w) };
        half8_t a1t = { (_Float16)(f1.x * T2.x), (_Float16)(f1.y * T2.y),
                        (_Float16)(f1.z * T2.z), (_Float16)(f1.w * T2.w),
                        (_Float16)(g1.x * T3.x), (_Float16)(g1.y * T3.y),
                        (_Float16)(g1.z * T3.z), (_Float16)(g1.w * T3.w) };

        float s0 = 0.f, s1 = 0.f, s2 = 0.f, s3 = 0.f;
        #pragma unroll
        for (int nt = 0; nt < 6; ++nt) {
            half8_t wa0 = *(const half8_t*)(waB + nt * 1024);
            half8_t wa1 = *(const half8_t*)(waB + nt * 1024 + 32);
            half8_t wb0 = *(const half8_t*)(wbB + nt * 1024);
            half8_t wb1 = *(const half8_t*)(wbB + nt * 1024 + 32);
            floatx4 acc = {0.f, 0.f, 0.f, 0.f};
            acc = __builtin_amdgcn_mfma_f32_16x16x32_f16(a0,  wa0, acc, 0, 0, 0);
            acc = __builtin_amdgcn_mfma_f32_16x16x32_f16(a1,  wa1, acc, 0, 0, 0);
            acc = __builtin_amdgcn_mfma_f32_16x16x32_f16(a0t, wb0, acc, 0, 0, 0);
            acc = __builtin_amdgcn_mfma_f32_16x16x32_f16(a1t, wb1, acc, 0, 0, 0);
            float be_n = beS[nt * 16 + lm];
            float w2   = aW2S[nt * 16 + lm];
            s0 += fmaxf(acc[0] + be_n, 0.f) * w2;
            s1 += fmaxf(acc[1] + be_n, 0.f) * w2;
            s2 += fmaxf(acc[2] + be_n, 0.f) * w2;
            s3 += fmaxf(acc[3] + be_n, 0.f) * w2;
        }
        #pragma unroll
        for (int off = 1; off < 16; off <<= 1) {
            s0 += __shfl_xor(s0, off);
            s1 += __shfl_xor(s1, off);
            s2 += __shfl_xor(s2, off);
            s3 += __shfl_xor(s3, off);
        }
        float v0 = __shfl(s0, qs16), v1 = __shfl(s1, qs16);
        float v2 = __shfl(s2, qs16), v3 = __shfl(s3, qs16);
        float aij = (rsel == 0) ? v0 : (rsel == 1) ? v1 : (rsel == 2) ? v2 : v3;
        aij += ab2S;
        aij = (row < M) ? aij : 0.f;

        tk0[0] += f0.x * aij; tk0[1] += f0.y * aij;
        tk0[2] += f0.z * aij; tk0[3] += f0.w * aij;
        tk0[4] += g0.x * aij; tk0[5] += g0.y * aij;
        tk0[6] += g0.z * aij; tk0[7] += g0.w * aij;
        tk1[0] += f1.x * aij; tk1[1] += f1.y * aij;
        tk1[2] += f1.z * aij; tk1[3] += f1.w * aij;
        tk1[4] += g1.x * aij; tk1[5] += g1.y * aij;
        tk1[6] += g1.z * aij; tk1[7] += g1.w * aij;
    }

    // ---- Phase C: reduce tk over quad lanes, write per-wave partials --
    #pragma unroll
    for (int j = 0; j < 8; ++j) {
        #pragma unroll
        for (int off = 1; off < 16; off <<= 1) {
            tk0[j] += __shfl_xor(tk0[j], off);
            tk1[j] += __shfl_xor(tk1[j], off);
        }
    }
    if (lm == 0) {
        #pragma unroll
        for (int j = 0; j < 8; ++j) {
            scr[wv * E + quad * 8 + j]      = tk0[j];
            scr[wv * E + 32 + quad * 8 + j] = tk1[j];
        }
    }
    __syncthreads();

    // x = [tmp | target | other]
    if (t < 64)
        xS[t] = (scr[t] + scr[64 + t]) + (scr[128 + t] + scr[192 + t]);
    else if (t < 128)
        xS[t] = tgtS[t - 64];
    else
        xS[t] = oth;
    __syncthreads();

    // ---- Phase D: MLP head --------------------------------------------
    // h1: 128 outs, 256-dot; thread (g=t&31, s=t>>5): outs 4g..4g+3,
    // c in [32s, 32s+32); float4 weight loads; lane^32 combine
    {
        const int g = t & 31, s = t >> 5;
        const float* wbase = oW1 + 4 * g;
        const int c0 = s * 32;
        float ax = 0.f, ay = 0.f, az = 0.f, aw = 0.f;
        #pragma unroll 8
        for (int i = 0; i < 32; ++i) {
            const int c = c0 + i;
            float xv = xS[c];
            float4 w4 = *(const float4*)(wbase + (size_t)c * F1);
            ax += xv * w4.x; ay += xv * w4.y;
            az += xv * w4.z; aw += xv * w4.w;
        }
        ax += __shfl_xor(ax, 32);
        ay += __shfl_xor(ay, 32);
        az += __shfl_xor(az, 32);
        aw += __shfl_xor(aw, 32);
        if (lane < 32) {
            float4 r = { ax, ay, az, aw };
            *(float4*)&scr[wv * 128 + 4 * g] = r;
        }
    }
    __syncthreads();
    if (t < F1)
        h1S[t] = fmaxf((scr[t] + scr[128 + t]) + (scr[256 + t] + scr[384 + t]) + ob1[t], 0.f);
    __syncthreads();

    // h2: 85 outs, 128-dot, split 2 ways over c
    {
        const int o = t & 127, ph = t >> 7;
        if (o < F2) {
            float sA = 0.f, sB = 0.f;
            const int c0 = ph * 64;
            #pragma unroll 8
            for (int c = 0; c < 64; c += 2) {
                sA += h1S[c0 + c]     * oW2[(size_t)(c0 + c) * F2 + o];
                sB += h1S[c0 + c + 1] * oW2[(size_t)(c0 + c + 1) * F2 + o];
            }
            scr[ph * 128 + o] = sA + sB;
        }
    }
    __syncthreads();
    if (t < F2) h2S[t] = fmaxf(scr[t] + scr[128 + t] + ob2[t], 0.f);
    __syncthreads();

    // h3: 64 outs, 85-dot, split 4 ways over c (all 256 threads)
    {
        const int o = t & 63, ph = t >> 6;
        const int c0 = (85 * ph) >> 2, c1 = (85 * (ph + 1)) >> 2;
        float s = 0.f;
        for (int c = c0; c < c1; ++c)
            s += h2S[c] * oW3[(size_t)c * F3 + o];
        scr[ph * 64 + o] = s;
    }
    __syncthreads();

    if (t < 64) {
        float v = fmaxf((scr[t] + scr[64 + t]) + (scr[128 + t] + scr[192 + t]) + ob3[t], 0.f) * fW[t];
        v += __shfl_xor(v, 1);  v += __shfl_xor(v, 2);  v += __shfl_xor(v, 4);
        v += __shfl_xor(v, 8);  v += __shfl_xor(v, 16); v += __shfl_xor(v, 32);
        if (t == 0) out[b] = 1.f / (1.f + __expf(-(v + fb[0])));
    }
}

extern "C" void kernel_launch(void* const* d_in, const int* in_sizes, int n_in,
                              void* d_out, int out_size, void* d_ws, size_t ws_size,
                              hipStream_t stream) {
    const float* hist   = (const float*)d_in[0];
    const float* target = (const float*)d_in[1];
    const float* other  = (const float*)d_in[2];
    const float* aW1    = (const float*)d_in[3];
    const float* ab1    = (const float*)d_in[4];
    const float* aW2    = (const float*)d_in[5];
    const float* ab2    = (const float*)d_in[6];
    const float* oW1    = (const float*)d_in[7];
    const float* ob1    = (const float*)d_in[8];
    const float* oW2    = (const float*)d_in[9];
    const float* ob2    = (const float*)d_in[10];
    const float* oW3    = (const float*)d_in[11];
    const float* ob3    = (const float*)d_in[12];
    const float* fW     = (const float*)d_in[13];
    const float* fb     = (const float*)d_in[14];
    float* out = (float*)d_out;

    _Float16* waT = (_Float16*)d_ws;             // 96*64 halfs = 12288 B
    _Float16* wbT = waT + H1 * E;                // 96*64 halfs = 12288 B

    din_prep<<<H1, E, 0, stream>>>(aW1, waT, wbT);
    din_kernel<<<BATCH, 256, 0, stream>>>(hist, target, other,
                                          waT, wbT,
                                          aW1, ab1, aW2, ab2,
                                          oW1, ob1, oW2, ob2, oW3, ob3,
                                          fW, fb, out);
}